// Round 1
// baseline (227.187 us; speedup 1.0000x reference)
//
#include <hip/hip_runtime.h>
#include <hip/hip_bf16.h>

#define HDIM 768
#define NH 12
#define HD 64
#define BB 8
#define SS 1024
#define MROWS (BB*SS)      // 8192
#define NQKV (3*HDIM)      // 2304

typedef __attribute__((ext_vector_type(8))) short bf16x8;
typedef __attribute__((ext_vector_type(4))) float f32x4;

__device__ __forceinline__ unsigned short f2bf(float f) {
    unsigned int u = __float_as_uint(f);
    unsigned int r = (u + 0x7fffu + ((u >> 16) & 1u)) >> 16;   // RNE
    return (unsigned short)r;
}

__device__ __forceinline__ void gload_lds16(const void* gsrc, void* ldst) {
    __builtin_amdgcn_global_load_lds(
        (const __attribute__((address_space(1))) unsigned int*)gsrc,
        (__attribute__((address_space(3))) unsigned int*)ldst,
        16, 0, 0);
}

// ---------------- pack kernels ----------------
__global__ void pack_bf16(const float* __restrict__ src, unsigned short* __restrict__ dst, int n4) {
    int stride = gridDim.x * blockDim.x;
    for (int i = blockIdx.x * blockDim.x + threadIdx.x; i < n4; i += stride) {
        float4 v = reinterpret_cast<const float4*>(src)[i];
        union { unsigned short u[4]; unsigned long long q; } o;
        o.u[0] = f2bf(v.x); o.u[1] = f2bf(v.y); o.u[2] = f2bf(v.z); o.u[3] = f2bf(v.w);
        reinterpret_cast<unsigned long long*>(dst)[i] = o.q;
    }
}

__global__ void pack_bias(const float* __restrict__ bq, const float* __restrict__ bk,
                          const float* __restrict__ bv, float* __restrict__ dst) {
    int i = blockIdx.x * blockDim.x + threadIdx.x;
    if (i >= 3 * HDIM) return;
    float v = (i < HDIM) ? bq[i] : (i < 2 * HDIM) ? bk[i - HDIM] : bv[i - 2 * HDIM];
    dst[i] = v;
}

// ---------------- GEMM: C[m][n] = sum_k A[m][k] * Bw[n][k] + bias[n] ----------------
// MODE 0: scatter to q [b][h][s][d], k [b][h][s][d], v^T [b][h][d][s] (bf16)
// MODE 1: fout[m*768 + n] = value (f32)
template<int MODE>
__global__ __launch_bounds__(256)
void gemm_bt(const unsigned short* __restrict__ A,
             const unsigned short* __restrict__ Bw,
             const float* __restrict__ bias,
             unsigned short* __restrict__ qb,
             unsigned short* __restrict__ kb,
             unsigned short* __restrict__ vtb,
             float* __restrict__ fout,
             int K)
{
    __shared__ unsigned short As[128][64];
    __shared__ unsigned short Bs[128][64];
    const int tid  = threadIdx.x;
    const int wave = tid >> 6;
    const int lane = tid & 63;
    const int bm = blockIdx.x * 128;
    const int bn = blockIdx.y * 128;
    const int wm = (wave >> 1) * 64;
    const int wn = (wave & 1) * 64;
    const int lr  = lane & 15;
    const int lk  = (lane >> 4) * 8;
    const int srow = lane >> 3;         // 0..7
    const int scol = (lane & 7) * 8;    // element offset for 16B

    f32x4 zero4 = {0.f, 0.f, 0.f, 0.f};
    f32x4 acc[4][4];
#pragma unroll
    for (int i = 0; i < 4; i++)
#pragma unroll
        for (int j = 0; j < 4; j++) acc[i][j] = zero4;

    for (int k0 = 0; k0 < K; k0 += 64) {
#pragma unroll
        for (int jj = 0; jj < 4; ++jj) {
            int i = wave * 4 + jj;      // 0..15, 8 rows per issue
            gload_lds16(A  + (size_t)(bm + i * 8 + srow) * K + k0 + scol, &As[i * 8][0]);
            gload_lds16(Bw + (size_t)(bn + i * 8 + srow) * K + k0 + scol, &Bs[i * 8][0]);
        }
        __syncthreads();

        bf16x8 af[4][2], bf[4][2];
#pragma unroll
        for (int mi = 0; mi < 4; mi++)
#pragma unroll
            for (int kk = 0; kk < 2; kk++)
                af[mi][kk] = *(const bf16x8*)&As[wm + mi * 16 + lr][kk * 32 + lk];
#pragma unroll
        for (int ni = 0; ni < 4; ni++)
#pragma unroll
            for (int kk = 0; kk < 2; kk++)
                bf[ni][kk] = *(const bf16x8*)&Bs[wn + ni * 16 + lr][kk * 32 + lk];

#pragma unroll
        for (int kk = 0; kk < 2; kk++)
#pragma unroll
            for (int mi = 0; mi < 4; mi++)
#pragma unroll
                for (int ni = 0; ni < 4; ni++)
                    acc[mi][ni] = __builtin_amdgcn_mfma_f32_16x16x32_bf16(
                        af[mi][kk], bf[ni][kk], acc[mi][ni], 0, 0, 0);
        __syncthreads();
    }

    const int rgrp = lane >> 4;   // 0..3
#pragma unroll
    for (int mi = 0; mi < 4; mi++)
#pragma unroll
        for (int ni = 0; ni < 4; ni++)
#pragma unroll
            for (int r = 0; r < 4; r++) {
                int m = bm + wm + mi * 16 + rgrp * 4 + r;
                int n = bn + wn + ni * 16 + lr;
                float v = acc[mi][ni][r] + bias[n];
                if (MODE == 0) {
                    int which = n / HDIM;
                    int nn = n - which * HDIM;
                    int h = nn >> 6, d = nn & 63;
                    int b = m >> 10, s = m & 1023;
                    unsigned short bvv = f2bf(v);
                    if (which == 0)      qb [(((size_t)(b * NH + h)) * SS + s) * HD + d] = bvv;
                    else if (which == 1) kb [(((size_t)(b * NH + h)) * SS + s) * HD + d] = bvv;
                    else                 vtb[(((size_t)(b * NH + h)) * HD + d) * SS + s] = bvv;
                } else {
                    fout[(size_t)m * HDIM + n] = v;
                }
            }
}

// ---------------- flash attention ----------------
// grid: (S/64, NH, B), block 256 (4 waves x 16 q-rows)
__global__ __launch_bounds__(256)
void attn_kernel(const unsigned short* __restrict__ qb,
                 const unsigned short* __restrict__ kb,
                 const unsigned short* __restrict__ vtb,
                 const int* __restrict__ mask,
                 unsigned short* __restrict__ ctx)
{
    __shared__ unsigned short Ks[64][64];      // [token][d]
    __shared__ unsigned short Vs[64][64];      // [d][token]
    __shared__ unsigned short Ps[4][16][64];   // per-wave P [q][token]

    const int tid  = threadIdx.x;
    const int wave = tid >> 6;
    const int lane = tid & 63;
    const int qt = blockIdx.x;
    const int h  = blockIdx.y;
    const int b  = blockIdx.z;
    const int bh = b * NH + h;
    const int q0 = qt * 64 + wave * 16;
    const int lr  = lane & 15;
    const int lkg = lane >> 4;
    const int lk  = lkg * 8;
    const int srow = lane >> 3;
    const int scol = (lane & 7) * 8;

    const unsigned short* Qp = qb  + (size_t)bh * SS * HD;
    const unsigned short* Kp = kb  + (size_t)bh * SS * HD;
    const unsigned short* Vp = vtb + (size_t)bh * HD * SS;

    bf16x8 aq[2];
#pragma unroll
    for (int kk = 0; kk < 2; kk++)
        aq[kk] = *(const bf16x8*)&Qp[(size_t)(q0 + lr) * HD + kk * 32 + lk];

    f32x4 zero4 = {0.f, 0.f, 0.f, 0.f};
    f32x4 o[4];
#pragma unroll
    for (int i = 0; i < 4; i++) o[i] = zero4;
    float mrun[4], lrun[4];
#pragma unroll
    for (int r = 0; r < 4; r++) { mrun[r] = -__builtin_inff(); lrun[r] = 0.f; }

    for (int t0 = 0; t0 < SS; t0 += 64) {
#pragma unroll
        for (int jj = 0; jj < 2; ++jj) {
            int i = wave * 2 + jj;     // 0..7
            gload_lds16(Kp + (size_t)(t0 + i * 8 + srow) * HD + scol, &Ks[i * 8][0]);
            gload_lds16(Vp + (size_t)(i * 8 + srow) * SS + t0 + scol, &Vs[i * 8][0]);
        }
        __syncthreads();

        // QK^T: sacc[ni] covers token cols ni*16..+16 for this wave's 16 q rows
        f32x4 sacc[4];
#pragma unroll
        for (int ni = 0; ni < 4; ni++) sacc[ni] = zero4;
#pragma unroll
        for (int ni = 0; ni < 4; ni++)
#pragma unroll
            for (int kk = 0; kk < 2; kk++) {
                bf16x8 bk = *(const bf16x8*)&Ks[ni * 16 + lr][kk * 32 + lk];
                sacc[ni] = __builtin_amdgcn_mfma_f32_16x16x32_bf16(aq[kk], bk, sacc[ni], 0, 0, 0);
            }

        int mk[4];
#pragma unroll
        for (int ni = 0; ni < 4; ni++) mk[ni] = mask[b * SS + t0 + ni * 16 + lr];

        float p[4][4];   // [ni][r]
        float tmax[4];
#pragma unroll
        for (int r = 0; r < 4; r++) {
            float vm = -__builtin_inff();
#pragma unroll
            for (int ni = 0; ni < 4; ni++) {
                float sc = sacc[ni][r] * 0.125f;
                if (mk[ni] == 0) sc = -10000.0f;
                p[ni][r] = sc;
                vm = fmaxf(vm, sc);
            }
            vm = fmaxf(vm, __shfl_xor(vm, 1, 16));
            vm = fmaxf(vm, __shfl_xor(vm, 2, 16));
            vm = fmaxf(vm, __shfl_xor(vm, 4, 16));
            vm = fmaxf(vm, __shfl_xor(vm, 8, 16));
            tmax[r] = vm;
        }

#pragma unroll
        for (int r = 0; r < 4; r++) {
            float mnew  = fmaxf(mrun[r], tmax[r]);
            float alpha = __expf(mrun[r] - mnew);
            float psum = 0.f;
#pragma unroll
            for (int ni = 0; ni < 4; ni++) {
                float e = __expf(p[ni][r] - mnew);
                p[ni][r] = e;
                psum += e;
            }
            psum += __shfl_xor(psum, 1, 16);
            psum += __shfl_xor(psum, 2, 16);
            psum += __shfl_xor(psum, 4, 16);
            psum += __shfl_xor(psum, 8, 16);
            lrun[r] = lrun[r] * alpha + psum;
            mrun[r] = mnew;
#pragma unroll
            for (int ni = 0; ni < 4; ni++) o[ni][r] *= alpha;
#pragma unroll
            for (int ni = 0; ni < 4; ni++)
                Ps[wave][lkg * 4 + r][ni * 16 + lr] = f2bf(p[ni][r]);
        }
        __syncthreads();

        // PV: o[nd] covers d cols nd*16..+16
#pragma unroll
        for (int nd = 0; nd < 4; nd++)
#pragma unroll
            for (int ks = 0; ks < 2; ks++) {
                bf16x8 pa = *(const bf16x8*)&Ps[wave][lr][ks * 32 + lk];
                bf16x8 vb = *(const bf16x8*)&Vs[nd * 16 + lr][ks * 32 + lk];
                o[nd] = __builtin_amdgcn_mfma_f32_16x16x32_bf16(pa, vb, o[nd], 0, 0, 0);
            }
        __syncthreads();
    }

#pragma unroll
    for (int r = 0; r < 4; r++) {
        float inv = 1.0f / lrun[r];
        int grow = b * SS + qt * 64 + wave * 16 + lkg * 4 + r;
#pragma unroll
        for (int nd = 0; nd < 4; nd++)
            ctx[(size_t)grow * HDIM + h * HD + nd * 16 + lr] = f2bf(o[nd][r] * inv);
    }
}

// ---------------- launch ----------------
extern "C" void kernel_launch(void* const* d_in, const int* in_sizes, int n_in,
                              void* d_out, int out_size, void* d_ws, size_t ws_size,
                              hipStream_t stream)
{
    const float* x    = (const float*)d_in[0];
    const int*   amask= (const int*)d_in[1];
    const float* Wq   = (const float*)d_in[2];
    const float* bq   = (const float*)d_in[3];
    const float* Wk   = (const float*)d_in[4];
    const float* bk   = (const float*)d_in[5];
    const float* Wv   = (const float*)d_in[6];
    const float* bv   = (const float*)d_in[7];
    const float* Wo   = (const float*)d_in[8];
    const float* bo   = (const float*)d_in[9];
    float* out = (float*)d_out;

    char* ws = (char*)d_ws;
    unsigned short* xb   = (unsigned short*)(ws);                   // 8192*768*2  = 12582912
    unsigned short* wqkv = (unsigned short*)(ws + 12582912);        // 2304*768*2  = 3538944
    unsigned short* wo   = (unsigned short*)(ws + 16121856);        // 768*768*2   = 1179648
    float*          biasq= (float*)(ws + 17301504);                 // 2304*4      = 9216
    unsigned short* qb   = (unsigned short*)(ws + 17310720);        // 12582912
    unsigned short* kb   = (unsigned short*)(ws + 29893632);        // 12582912
    unsigned short* vtb  = (unsigned short*)(ws + 42476544);        // 12582912
    unsigned short* ctx  = (unsigned short*)(ws + 55059456);        // 12582912 -> ends 67642368

    pack_bf16<<<2048, 256, 0, stream>>>(x, xb, (MROWS * HDIM) / 4);
    pack_bf16<<<576, 256, 0, stream>>>(Wq, wqkv + 0,            (HDIM * HDIM) / 4);
    pack_bf16<<<576, 256, 0, stream>>>(Wk, wqkv + HDIM * HDIM,  (HDIM * HDIM) / 4);
    pack_bf16<<<576, 256, 0, stream>>>(Wv, wqkv + 2 * HDIM * HDIM, (HDIM * HDIM) / 4);
    pack_bf16<<<576, 256, 0, stream>>>(Wo, wo, (HDIM * HDIM) / 4);
    pack_bias<<<9, 256, 0, stream>>>(bq, bk, bv, biasq);

    gemm_bt<0><<<dim3(MROWS / 128, NQKV / 128), 256, 0, stream>>>(
        xb, wqkv, biasq, qb, kb, vtb, nullptr, HDIM);

    attn_kernel<<<dim3(SS / 64, NH, BB), 256, 0, stream>>>(qb, kb, vtb, amask, ctx);

    gemm_bt<1><<<dim3(MROWS / 128, HDIM / 128), 256, 0, stream>>>(
        ctx, wo, bo, nullptr, nullptr, nullptr, out, HDIM);
}

// Round 2
// 185.363 us; speedup vs baseline: 1.2256x; 1.2256x over previous
//
#include <hip/hip_runtime.h>
#include <hip/hip_bf16.h>

#define HDIM 768
#define NH 12
#define HD 64
#define BB 8
#define SS 1024
#define MROWS (BB*SS)      // 8192
#define NQKV (3*HDIM)      // 2304

typedef __attribute__((ext_vector_type(8))) short bf16x8;
typedef __attribute__((ext_vector_type(4))) float f32x4;

__device__ __forceinline__ unsigned short f2bf(float f) {
    unsigned int u = __float_as_uint(f);
    unsigned int r = (u + 0x7fffu + ((u >> 16) & 1u)) >> 16;   // RNE
    return (unsigned short)r;
}

__device__ __forceinline__ void gload_lds16(const void* gsrc, void* ldst) {
    __builtin_amdgcn_global_load_lds(
        (const __attribute__((address_space(1))) unsigned int*)gsrc,
        (__attribute__((address_space(3))) unsigned int*)ldst,
        16, 0, 0);
}

// ---------------- pack kernels ----------------
__global__ void pack_bf16(const float* __restrict__ src, unsigned short* __restrict__ dst, int n4) {
    int stride = gridDim.x * blockDim.x;
    for (int i = blockIdx.x * blockDim.x + threadIdx.x; i < n4; i += stride) {
        float4 v = reinterpret_cast<const float4*>(src)[i];
        union { unsigned short u[4]; unsigned long long q; } o;
        o.u[0] = f2bf(v.x); o.u[1] = f2bf(v.y); o.u[2] = f2bf(v.z); o.u[3] = f2bf(v.w);
        reinterpret_cast<unsigned long long*>(dst)[i] = o.q;
    }
}

__global__ void pack_bias(const float* __restrict__ bq, const float* __restrict__ bk,
                          const float* __restrict__ bv, float* __restrict__ dst) {
    int i = blockIdx.x * blockDim.x + threadIdx.x;
    if (i >= 3 * HDIM) return;
    float v = (i < HDIM) ? bq[i] : (i < 2 * HDIM) ? bk[i - HDIM] : bv[i - 2 * HDIM];
    dst[i] = v;
}

// ---------------- GEMM: C[m][n] = sum_k A[m][k] * Bw[n][k] + bias[n] ----------------
// MODE 0: scatter to q [b][h][s][d], k [b][h][s][d], v^T [b][h][d][s] (bf16)
// MODE 1: fout[m*768 + n] = value (f32)
template<int MODE>
__global__ __launch_bounds__(256)
void gemm_bt(const unsigned short* __restrict__ A,
             const unsigned short* __restrict__ Bw,
             const float* __restrict__ bias,
             unsigned short* __restrict__ qb,
             unsigned short* __restrict__ kb,
             unsigned short* __restrict__ vtb,
             float* __restrict__ fout,
             int K)
{
    __shared__ unsigned short As[128][64];
    __shared__ unsigned short Bs[128][64];
    const int tid  = threadIdx.x;
    const int wave = tid >> 6;
    const int lane = tid & 63;
    const int bm = blockIdx.x * 128;
    const int bn = blockIdx.y * 128;
    const int wm = (wave >> 1) * 64;
    const int wn = (wave & 1) * 64;
    const int lr  = lane & 15;
    const int lk  = (lane >> 4) * 8;
    const int srow = lane >> 3;         // 0..7
    const int scol = (lane & 7) * 8;    // element offset for 16B

    f32x4 zero4 = {0.f, 0.f, 0.f, 0.f};
    f32x4 acc[4][4];
#pragma unroll
    for (int i = 0; i < 4; i++)
#pragma unroll
        for (int j = 0; j < 4; j++) acc[i][j] = zero4;

    for (int k0 = 0; k0 < K; k0 += 64) {
#pragma unroll
        for (int jj = 0; jj < 4; ++jj) {
            int i = wave * 4 + jj;      // 0..15, 8 rows per issue
            gload_lds16(A  + (size_t)(bm + i * 8 + srow) * K + k0 + scol, &As[i * 8][0]);
            gload_lds16(Bw + (size_t)(bn + i * 8 + srow) * K + k0 + scol, &Bs[i * 8][0]);
        }
        __syncthreads();

        bf16x8 af[4][2], bf[4][2];
#pragma unroll
        for (int mi = 0; mi < 4; mi++)
#pragma unroll
            for (int kk = 0; kk < 2; kk++)
                af[mi][kk] = *(const bf16x8*)&As[wm + mi * 16 + lr][kk * 32 + lk];
#pragma unroll
        for (int ni = 0; ni < 4; ni++)
#pragma unroll
            for (int kk = 0; kk < 2; kk++)
                bf[ni][kk] = *(const bf16x8*)&Bs[wn + ni * 16 + lr][kk * 32 + lk];

#pragma unroll
        for (int kk = 0; kk < 2; kk++)
#pragma unroll
            for (int mi = 0; mi < 4; mi++)
#pragma unroll
                for (int ni = 0; ni < 4; ni++)
                    acc[mi][ni] = __builtin_amdgcn_mfma_f32_16x16x32_bf16(
                        af[mi][kk], bf[ni][kk], acc[mi][ni], 0, 0, 0);
        __syncthreads();
    }

    const int rgrp = lane >> 4;   // 0..3
#pragma unroll
    for (int mi = 0; mi < 4; mi++)
#pragma unroll
        for (int ni = 0; ni < 4; ni++)
#pragma unroll
            for (int r = 0; r < 4; r++) {
                int m = bm + wm + mi * 16 + rgrp * 4 + r;
                int n = bn + wn + ni * 16 + lr;
                float v = acc[mi][ni][r] + bias[n];
                if (MODE == 0) {
                    int which = n / HDIM;
                    int nn = n - which * HDIM;
                    int h = nn >> 6, d = nn & 63;
                    int b = m >> 10, s = m & 1023;
                    unsigned short bvv = f2bf(v);
                    if (which == 0)      qb [(((size_t)(b * NH + h)) * SS + s) * HD + d] = bvv;
                    else if (which == 1) kb [(((size_t)(b * NH + h)) * SS + s) * HD + d] = bvv;
                    else                 vtb[(((size_t)(b * NH + h)) * HD + d) * SS + s] = bvv;
                } else {
                    fout[(size_t)m * HDIM + n] = v;
                }
            }
}

// ---------------- flash attention (swapped-QK^T, swizzled LDS, double-buffered) ----------------
// grid: (S/64, NH, B), block 256 (4 waves x 16 q-rows)
__global__ __launch_bounds__(256)
void attn_kernel(const unsigned short* __restrict__ qb,
                 const unsigned short* __restrict__ kb,
                 const unsigned short* __restrict__ vtb,
                 const int* __restrict__ mask,
                 unsigned short* __restrict__ ctx)
{
    // Ks/Vs: 16B-granule XOR swizzle (granule ^= row&7), written pre-swizzled via global src.
    __shared__ unsigned short Ks[2][64][64];   // [buf][token][d]
    __shared__ unsigned short Vs[2][64][64];   // [buf][d][token]
    __shared__ unsigned short Ps[4][16][64];   // per-wave P [q][token], 8B-chunk swizzle

    const int tid  = threadIdx.x;
    const int wave = tid >> 6;
    const int lane = tid & 63;
    const int qt = blockIdx.x;
    const int h  = blockIdx.y;
    const int b  = blockIdx.z;
    const int bh = b * NH + h;
    const int q0 = qt * 64 + wave * 16;
    const int lr  = lane & 15;
    const int hi  = lane >> 4;          // 0..3
    const int e3  = lr & 7;             // read-side row xor
    const int srow = lane >> 3;         // staging: row within 8-row group
    const int sg   = lane & 7;          // staging: LDS granule index

    const unsigned short* Qp = qb  + (size_t)bh * SS * HD;
    const unsigned short* Kp = kb  + (size_t)bh * SS * HD;
    const unsigned short* Vp = vtb + (size_t)bh * HD * SS;

    // Q fragment (B-operand of mfma(K,Q)): lane holds q = q0+lr, d = kk*32 + hi*8 + j
    bf16x8 aq[2];
#pragma unroll
    for (int kk = 0; kk < 2; kk++)
        aq[kk] = *(const bf16x8*)&Qp[(size_t)(q0 + lr) * HD + kk * 32 + hi * 8];

    f32x4 zero4 = {0.f, 0.f, 0.f, 0.f};
    f32x4 o[4];
#pragma unroll
    for (int i = 0; i < 4; i++) o[i] = zero4;
    float mrun = -__builtin_inff();
    float lrun = 0.f;

    // stage tile t0 into buffer buf (pre-swizzled source granule)
    auto stage = [&](int buf, int t0) {
#pragma unroll
        for (int jj = 0; jj < 2; ++jj) {
            int i = wave * 2 + jj;               // 0..7
            int rr = i * 8 + srow;               // row 0..63
            int gk = sg ^ (rr & 7);              // global granule to fetch
            gload_lds16(Kp + (size_t)(t0 + rr) * HD + gk * 8, &Ks[buf][i * 8][0]);
            gload_lds16(Vp + (size_t)rr * SS + t0 + gk * 8,   &Vs[buf][i * 8][0]);
        }
    };

    stage(0, 0);
    __syncthreads();

    int buf = 0;
    for (int t0 = 0; t0 < SS; t0 += 64) {
        if (t0 + 64 < SS) stage(buf ^ 1, t0 + 64);

        // QK^T swapped: sacc[ni] = K-tile(ni) x Q^T -> row = token(ni*16+4hi+r), col = q(lr)
        f32x4 sacc[4];
#pragma unroll
        for (int ni = 0; ni < 4; ni++) sacc[ni] = zero4;
#pragma unroll
        for (int kk = 0; kk < 2; kk++)
#pragma unroll
            for (int ni = 0; ni < 4; ni++) {
                bf16x8 kf = *(const bf16x8*)&Ks[buf][ni * 16 + lr][((kk * 4 + hi) ^ e3) * 8];
                sacc[ni] = __builtin_amdgcn_mfma_f32_16x16x32_bf16(kf, aq[kk], sacc[ni], 0, 0, 0);
            }

        // masks for tokens ni*16 + 4*hi + {0..3}
        int4 mv[4];
#pragma unroll
        for (int ni = 0; ni < 4; ni++)
            mv[ni] = *(const int4*)&mask[b * SS + t0 + ni * 16 + hi * 4];

        float sc[4][4];
        float vmax = -__builtin_inff();
#pragma unroll
        for (int ni = 0; ni < 4; ni++) {
            sc[ni][0] = (mv[ni].x == 0) ? -10000.0f : sacc[ni][0] * 0.125f;
            sc[ni][1] = (mv[ni].y == 0) ? -10000.0f : sacc[ni][1] * 0.125f;
            sc[ni][2] = (mv[ni].z == 0) ? -10000.0f : sacc[ni][2] * 0.125f;
            sc[ni][3] = (mv[ni].w == 0) ? -10000.0f : sacc[ni][3] * 0.125f;
#pragma unroll
            for (int r = 0; r < 4; r++) vmax = fmaxf(vmax, sc[ni][r]);
        }
        // lane holds 16 of the 64 tokens for q=lr; combine across the 4 hi-groups
        vmax = fmaxf(vmax, __shfl_xor(vmax, 16));
        vmax = fmaxf(vmax, __shfl_xor(vmax, 32));

        float mnew  = fmaxf(mrun, vmax);
        float alpha = __expf(mrun - mnew);
        float psum = 0.f;
#pragma unroll
        for (int ni = 0; ni < 4; ni++)
#pragma unroll
            for (int r = 0; r < 4; r++) {
                float e = __expf(sc[ni][r] - mnew);
                sc[ni][r] = e;
                psum += e;
            }
        psum += __shfl_xor(psum, 16);
        psum += __shfl_xor(psum, 32);
        lrun = lrun * alpha + psum;
        mrun = mnew;

        // write P (bf16) : Ps[q=lr][tok], 8B chunks swizzled with (e3<<1)
#pragma unroll
        for (int ni = 0; ni < 4; ni++) {
            unsigned long long w =
                (unsigned long long)f2bf(sc[ni][0])
              | ((unsigned long long)f2bf(sc[ni][1]) << 16)
              | ((unsigned long long)f2bf(sc[ni][2]) << 32)
              | ((unsigned long long)f2bf(sc[ni][3]) << 48);
            *(unsigned long long*)&Ps[wave][lr][((4 * ni + hi) ^ (e3 << 1)) * 4] = w;
        }

        // rescale O rows (o row r corresponds to q = 4*hi + r; alpha lives at lane lr=q)
        float aR[4];
#pragma unroll
        for (int r = 0; r < 4; r++) aR[r] = __shfl(alpha, hi * 4 + r, 16);
#pragma unroll
        for (int nd = 0; nd < 4; nd++)
#pragma unroll
            for (int r = 0; r < 4; r++) o[nd][r] *= aR[r];

        // PV: o[nd] (+= P x V), A = P from LDS, B = V^T from LDS
#pragma unroll
        for (int ks = 0; ks < 2; ks++) {
            bf16x8 pa = *(const bf16x8*)&Ps[wave][lr][((8 * ks + 2 * hi) ^ (e3 << 1)) * 4];
#pragma unroll
            for (int nd = 0; nd < 4; nd++) {
                bf16x8 vb = *(const bf16x8*)&Vs[buf][nd * 16 + lr][((4 * ks + hi) ^ e3) * 8];
                o[nd] = __builtin_amdgcn_mfma_f32_16x16x32_bf16(pa, vb, o[nd], 0, 0, 0);
            }
        }

        __syncthreads();   // drains stage loads (compiler emits vmcnt(0)) + guards buf swap
        buf ^= 1;
    }

    // epilogue: normalize and write ctx
    float iv[4];
#pragma unroll
    for (int r = 0; r < 4; r++) iv[r] = 1.0f / __shfl(lrun, hi * 4 + r, 16);
#pragma unroll
    for (int r = 0; r < 4; r++) {
        int grow = b * SS + qt * 64 + wave * 16 + hi * 4 + r;
#pragma unroll
        for (int nd = 0; nd < 4; nd++)
            ctx[(size_t)grow * HDIM + h * HD + nd * 16 + lr] = f2bf(o[nd][r] * iv[r]);
    }
}

// ---------------- launch ----------------
extern "C" void kernel_launch(void* const* d_in, const int* in_sizes, int n_in,
                              void* d_out, int out_size, void* d_ws, size_t ws_size,
                              hipStream_t stream)
{
    const float* x    = (const float*)d_in[0];
    const int*   amask= (const int*)d_in[1];
    const float* Wq   = (const float*)d_in[2];
    const float* bq   = (const float*)d_in[3];
    const float* Wk   = (const float*)d_in[4];
    const float* bk   = (const float*)d_in[5];
    const float* Wv   = (const float*)d_in[6];
    const float* bv   = (const float*)d_in[7];
    const float* Wo   = (const float*)d_in[8];
    const float* bo   = (const float*)d_in[9];
    float* out = (float*)d_out;

    char* ws = (char*)d_ws;
    unsigned short* xb   = (unsigned short*)(ws);                   // 8192*768*2  = 12582912
    unsigned short* wqkv = (unsigned short*)(ws + 12582912);        // 2304*768*2  = 3538944
    unsigned short* wo   = (unsigned short*)(ws + 16121856);        // 768*768*2   = 1179648
    float*          biasq= (float*)(ws + 17301504);                 // 2304*4      = 9216
    unsigned short* qb   = (unsigned short*)(ws + 17310720);        // 12582912
    unsigned short* kb   = (unsigned short*)(ws + 29893632);        // 12582912
    unsigned short* vtb  = (unsigned short*)(ws + 42476544);        // 12582912
    unsigned short* ctx  = (unsigned short*)(ws + 55059456);        // 12582912 -> ends 67642368

    pack_bf16<<<2048, 256, 0, stream>>>(x, xb, (MROWS * HDIM) / 4);
    pack_bf16<<<576, 256, 0, stream>>>(Wq, wqkv + 0,            (HDIM * HDIM) / 4);
    pack_bf16<<<576, 256, 0, stream>>>(Wk, wqkv + HDIM * HDIM,  (HDIM * HDIM) / 4);
    pack_bf16<<<576, 256, 0, stream>>>(Wv, wqkv + 2 * HDIM * HDIM, (HDIM * HDIM) / 4);
    pack_bf16<<<576, 256, 0, stream>>>(Wo, wo, (HDIM * HDIM) / 4);
    pack_bias<<<9, 256, 0, stream>>>(bq, bk, bv, biasq);

    gemm_bt<0><<<dim3(MROWS / 128, NQKV / 128), 256, 0, stream>>>(
        xb, wqkv, biasq, qb, kb, vtb, nullptr, HDIM);

    attn_kernel<<<dim3(SS / 64, NH, BB), 256, 0, stream>>>(qb, kb, vtb, amask, ctx);

    gemm_bt<1><<<dim3(MROWS / 128, HDIM / 128), 256, 0, stream>>>(
        ctx, wo, bo, nullptr, nullptr, nullptr, out, HDIM);
}

// Round 3
// 179.309 us; speedup vs baseline: 1.2670x; 1.0338x over previous
//
#include <hip/hip_runtime.h>
#include <hip/hip_bf16.h>

#define HDIM 768
#define NH 12
#define HD 64
#define BB 8
#define SS 1024
#define MROWS (BB*SS)      // 8192
#define NQKV (3*HDIM)      // 2304

typedef __attribute__((ext_vector_type(8))) short bf16x8;
typedef __attribute__((ext_vector_type(4))) float f32x4;

__device__ __forceinline__ unsigned short f2bf(float f) {
    unsigned int u = __float_as_uint(f);
    unsigned int r = (u + 0x7fffu + ((u >> 16) & 1u)) >> 16;   // RNE
    return (unsigned short)r;
}

__device__ __forceinline__ void gload_lds16(const void* gsrc, void* ldst) {
    __builtin_amdgcn_global_load_lds(
        (const __attribute__((address_space(1))) unsigned int*)gsrc,
        (__attribute__((address_space(3))) unsigned int*)ldst,
        16, 0, 0);
}

// ---------------- pack kernels ----------------
__global__ void pack_bf16(const float* __restrict__ src, unsigned short* __restrict__ dst, int n4) {
    int stride = gridDim.x * blockDim.x;
    for (int i = blockIdx.x * blockDim.x + threadIdx.x; i < n4; i += stride) {
        float4 v = reinterpret_cast<const float4*>(src)[i];
        union { unsigned short u[4]; unsigned long long q; } o;
        o.u[0] = f2bf(v.x); o.u[1] = f2bf(v.y); o.u[2] = f2bf(v.z); o.u[3] = f2bf(v.w);
        reinterpret_cast<unsigned long long*>(dst)[i] = o.q;
    }
}

// all 4 weight matrices in one launch: 4 segments x 576 blocks x 256 thr (147456 float4 each)
__global__ void pack_weights(const float* __restrict__ Wq, const float* __restrict__ Wk,
                             const float* __restrict__ Wv, const float* __restrict__ Wo,
                             unsigned short* __restrict__ wqkv, unsigned short* __restrict__ wo) {
    int seg = blockIdx.x / 576;
    int idx = (blockIdx.x % 576) * 256 + threadIdx.x;   // < 147456
    const float* src = (seg == 0) ? Wq : (seg == 1) ? Wk : (seg == 2) ? Wv : Wo;
    unsigned short* dst = (seg == 0) ? wqkv : (seg == 1) ? wqkv + HDIM * HDIM
                        : (seg == 2) ? wqkv + 2 * HDIM * HDIM : wo;
    float4 v = reinterpret_cast<const float4*>(src)[idx];
    union { unsigned short u[4]; unsigned long long q; } o;
    o.u[0] = f2bf(v.x); o.u[1] = f2bf(v.y); o.u[2] = f2bf(v.z); o.u[3] = f2bf(v.w);
    reinterpret_cast<unsigned long long*>(dst)[idx] = o.q;
}

__global__ void pack_bias(const float* __restrict__ bq, const float* __restrict__ bk,
                          const float* __restrict__ bv, float* __restrict__ dst) {
    int i = blockIdx.x * blockDim.x + threadIdx.x;
    if (i >= 3 * HDIM) return;
    float v = (i < HDIM) ? bq[i] : (i < 2 * HDIM) ? bk[i - HDIM] : bv[i - 2 * HDIM];
    dst[i] = v;
}

// ---------------- GEMM: C[m][n] = sum_k A[m][k] * Bw[n][k] + bias[n] ----------------
// min-2-phase: double-buffered LDS, stage(k+1) issued before compute(k), ONE barrier/tile.
// MODE 0: scatter to q [b][h][s][d], k [b][h][s][d], v^T [b][h][d][s] (bf16)
// MODE 1: fout[m*768 + n] = value (f32)
template<int MODE>
__global__ __launch_bounds__(256, 2)
void gemm_bt(const unsigned short* __restrict__ A,
             const unsigned short* __restrict__ Bw,
             const float* __restrict__ bias,
             unsigned short* __restrict__ qb,
             unsigned short* __restrict__ kb,
             unsigned short* __restrict__ vtb,
             float* __restrict__ fout,
             int K, int gridN)
{
    __shared__ unsigned short As[2][128 * 64];
    __shared__ unsigned short Bs[2][128 * 64];
    const int tid  = threadIdx.x;
    const int wave = tid >> 6;
    const int lane = tid & 63;

    // bijective XCD swizzle (nwg % 8 == 0), N-fastest within chunk
    const int nwg = gridDim.x;
    const int cpx = nwg >> 3;
    const int wg  = (blockIdx.x & 7) * cpx + (blockIdx.x >> 3);
    const int bm = (wg / gridN) * 128;
    const int bn = (wg % gridN) * 128;

    const int wm = (wave >> 1) * 64;
    const int wn = (wave & 1) * 64;
    const int lr  = lane & 15;
    const int lk  = (lane >> 4) * 8;
    const int srow = lane >> 3;         // 0..7
    const int scol = (lane & 7) * 8;    // element offset for 16B

    f32x4 zero4 = {0.f, 0.f, 0.f, 0.f};
    f32x4 acc[4][4];
#pragma unroll
    for (int i = 0; i < 4; i++)
#pragma unroll
        for (int j = 0; j < 4; j++) acc[i][j] = zero4;

    auto stage = [&](int buf, int k0) {
#pragma unroll
        for (int jj = 0; jj < 4; ++jj) {
            int i = wave * 4 + jj;      // 0..15 row-groups of 8
            gload_lds16(A  + (size_t)(bm + i * 8 + srow) * K + k0 + scol, &As[buf][i * 8 * 64]);
            gload_lds16(Bw + (size_t)(bn + i * 8 + srow) * K + k0 + scol, &Bs[buf][i * 8 * 64]);
        }
    };

    stage(0, 0);
    __syncthreads();

    int buf = 0;
    for (int k0 = 0; k0 < K; k0 += 64) {
        if (k0 + 64 < K) stage(buf ^ 1, k0 + 64);

        bf16x8 af[4][2], bf[4][2];
#pragma unroll
        for (int mi = 0; mi < 4; mi++)
#pragma unroll
            for (int kk = 0; kk < 2; kk++)
                af[mi][kk] = *(const bf16x8*)&As[buf][(wm + mi * 16 + lr) * 64 + kk * 32 + lk];
#pragma unroll
        for (int ni = 0; ni < 4; ni++)
#pragma unroll
            for (int kk = 0; kk < 2; kk++)
                bf[ni][kk] = *(const bf16x8*)&Bs[buf][(wn + ni * 16 + lr) * 64 + kk * 32 + lk];

#pragma unroll
        for (int kk = 0; kk < 2; kk++)
#pragma unroll
            for (int mi = 0; mi < 4; mi++)
#pragma unroll
                for (int ni = 0; ni < 4; ni++)
                    acc[mi][ni] = __builtin_amdgcn_mfma_f32_16x16x32_bf16(
                        af[mi][kk], bf[ni][kk], acc[mi][ni], 0, 0, 0);

        __syncthreads();   // drains stage (vmcnt) + protects buffer being restaged next iter
        buf ^= 1;
    }

    const int rgrp = lane >> 4;   // 0..3
#pragma unroll
    for (int mi = 0; mi < 4; mi++)
#pragma unroll
        for (int ni = 0; ni < 4; ni++)
#pragma unroll
            for (int r = 0; r < 4; r++) {
                int m = bm + wm + mi * 16 + rgrp * 4 + r;
                int n = bn + wn + ni * 16 + lr;
                float v = acc[mi][ni][r] + bias[n];
                if (MODE == 0) {
                    int which = n / HDIM;
                    int nn = n - which * HDIM;
                    int h = nn >> 6, d = nn & 63;
                    int b = m >> 10, s = m & 1023;
                    unsigned short bvv = f2bf(v);
                    if (which == 0)      qb [(((size_t)(b * NH + h)) * SS + s) * HD + d] = bvv;
                    else if (which == 1) kb [(((size_t)(b * NH + h)) * SS + s) * HD + d] = bvv;
                    else                 vtb[(((size_t)(b * NH + h)) * HD + d) * SS + s] = bvv;
                } else {
                    fout[(size_t)m * HDIM + n] = v;
                }
            }
}

// ---------------- flash attention (swapped-QK^T, swizzled LDS, double-buffered) ----------------
// grid: 1536 blocks (flattened b,h,qt with XCD swizzle), block 256 (4 waves x 16 q-rows)
__global__ __launch_bounds__(256)
void attn_kernel(const unsigned short* __restrict__ qb,
                 const unsigned short* __restrict__ kb,
                 const unsigned short* __restrict__ vtb,
                 const int* __restrict__ mask,
                 unsigned short* __restrict__ ctx)
{
    __shared__ unsigned short Ks[2][64][64];   // [buf][token][d]
    __shared__ unsigned short Vs[2][64][64];   // [buf][d][token]
    __shared__ unsigned short Ps[4][16][64];   // per-wave P [q][token], 8B-chunk swizzle

    const int tid  = threadIdx.x;
    const int wave = tid >> 6;
    const int lane = tid & 63;
    // XCD swizzle: each XCD gets one full batch (12 heads x 16 q-tiles -> K/V fits 4MB L2)
    const int wg = (blockIdx.x & 7) * 192 + (blockIdx.x >> 3);
    const int qt = wg & 15;
    const int h  = (wg >> 4) % NH;
    const int b  = wg / 192;
    const int bh = b * NH + h;
    const int q0 = qt * 64 + wave * 16;
    const int lr  = lane & 15;
    const int hi  = lane >> 4;          // 0..3
    const int e3  = lr & 7;             // read-side row xor
    const int srow = lane >> 3;         // staging: row within 8-row group
    const int sg   = lane & 7;          // staging: LDS granule index

    const unsigned short* Qp = qb  + (size_t)bh * SS * HD;
    const unsigned short* Kp = kb  + (size_t)bh * SS * HD;
    const unsigned short* Vp = vtb + (size_t)bh * HD * SS;

    bf16x8 aq[2];
#pragma unroll
    for (int kk = 0; kk < 2; kk++)
        aq[kk] = *(const bf16x8*)&Qp[(size_t)(q0 + lr) * HD + kk * 32 + hi * 8];

    f32x4 zero4 = {0.f, 0.f, 0.f, 0.f};
    f32x4 o[4];
#pragma unroll
    for (int i = 0; i < 4; i++) o[i] = zero4;
    float mrun = -__builtin_inff();
    float lrun = 0.f;

    auto stage = [&](int buf, int t0) {
#pragma unroll
        for (int jj = 0; jj < 2; ++jj) {
            int i = wave * 2 + jj;               // 0..7
            int rr = i * 8 + srow;               // row 0..63
            int gk = sg ^ (rr & 7);              // pre-swizzled source granule
            gload_lds16(Kp + (size_t)(t0 + rr) * HD + gk * 8, &Ks[buf][i * 8][0]);
            gload_lds16(Vp + (size_t)rr * SS + t0 + gk * 8,   &Vs[buf][i * 8][0]);
        }
    };

    stage(0, 0);
    __syncthreads();

    int buf = 0;
    for (int t0 = 0; t0 < SS; t0 += 64) {
        if (t0 + 64 < SS) stage(buf ^ 1, t0 + 64);

        // QK^T swapped: row = token(ni*16+4hi+r), col = q(lr)
        f32x4 sacc[4];
#pragma unroll
        for (int ni = 0; ni < 4; ni++) sacc[ni] = zero4;
#pragma unroll
        for (int kk = 0; kk < 2; kk++)
#pragma unroll
            for (int ni = 0; ni < 4; ni++) {
                bf16x8 kf = *(const bf16x8*)&Ks[buf][ni * 16 + lr][((kk * 4 + hi) ^ e3) * 8];
                sacc[ni] = __builtin_amdgcn_mfma_f32_16x16x32_bf16(kf, aq[kk], sacc[ni], 0, 0, 0);
            }

        int4 mv[4];
#pragma unroll
        for (int ni = 0; ni < 4; ni++)
            mv[ni] = *(const int4*)&mask[b * SS + t0 + ni * 16 + hi * 4];

        float sc[4][4];
        float vmax = -__builtin_inff();
#pragma unroll
        for (int ni = 0; ni < 4; ni++) {
            sc[ni][0] = (mv[ni].x == 0) ? -10000.0f : sacc[ni][0] * 0.125f;
            sc[ni][1] = (mv[ni].y == 0) ? -10000.0f : sacc[ni][1] * 0.125f;
            sc[ni][2] = (mv[ni].z == 0) ? -10000.0f : sacc[ni][2] * 0.125f;
            sc[ni][3] = (mv[ni].w == 0) ? -10000.0f : sacc[ni][3] * 0.125f;
#pragma unroll
            for (int r = 0; r < 4; r++) vmax = fmaxf(vmax, sc[ni][r]);
        }
        vmax = fmaxf(vmax, __shfl_xor(vmax, 16));
        vmax = fmaxf(vmax, __shfl_xor(vmax, 32));

        float mnew  = fmaxf(mrun, vmax);
        float alpha = __expf(mrun - mnew);
        float psum = 0.f;
#pragma unroll
        for (int ni = 0; ni < 4; ni++)
#pragma unroll
            for (int r = 0; r < 4; r++) {
                float e = __expf(sc[ni][r] - mnew);
                sc[ni][r] = e;
                psum += e;
            }
        psum += __shfl_xor(psum, 16);
        psum += __shfl_xor(psum, 32);
        lrun = lrun * alpha + psum;
        mrun = mnew;

#pragma unroll
        for (int ni = 0; ni < 4; ni++) {
            unsigned long long w =
                (unsigned long long)f2bf(sc[ni][0])
              | ((unsigned long long)f2bf(sc[ni][1]) << 16)
              | ((unsigned long long)f2bf(sc[ni][2]) << 32)
              | ((unsigned long long)f2bf(sc[ni][3]) << 48);
            *(unsigned long long*)&Ps[wave][lr][((4 * ni + hi) ^ (e3 << 1)) * 4] = w;
        }

        float aR[4];
#pragma unroll
        for (int r = 0; r < 4; r++) aR[r] = __shfl(alpha, hi * 4 + r, 16);
#pragma unroll
        for (int nd = 0; nd < 4; nd++)
#pragma unroll
            for (int r = 0; r < 4; r++) o[nd][r] *= aR[r];

#pragma unroll
        for (int ks = 0; ks < 2; ks++) {
            bf16x8 pa = *(const bf16x8*)&Ps[wave][lr][((8 * ks + 2 * hi) ^ (e3 << 1)) * 4];
#pragma unroll
            for (int nd = 0; nd < 4; nd++) {
                bf16x8 vb = *(const bf16x8*)&Vs[buf][nd * 16 + lr][((4 * ks + hi) ^ e3) * 8];
                o[nd] = __builtin_amdgcn_mfma_f32_16x16x32_bf16(pa, vb, o[nd], 0, 0, 0);
            }
        }

        __syncthreads();
        buf ^= 1;
    }

    float iv[4];
#pragma unroll
    for (int r = 0; r < 4; r++) iv[r] = 1.0f / __shfl(lrun, hi * 4 + r, 16);
#pragma unroll
    for (int r = 0; r < 4; r++) {
        int grow = b * SS + qt * 64 + wave * 16 + hi * 4 + r;
#pragma unroll
        for (int nd = 0; nd < 4; nd++)
            ctx[(size_t)grow * HDIM + h * HD + nd * 16 + lr] = f2bf(o[nd][r] * iv[r]);
    }
}

// ---------------- launch ----------------
extern "C" void kernel_launch(void* const* d_in, const int* in_sizes, int n_in,
                              void* d_out, int out_size, void* d_ws, size_t ws_size,
                              hipStream_t stream)
{
    const float* x    = (const float*)d_in[0];
    const int*   amask= (const int*)d_in[1];
    const float* Wq   = (const float*)d_in[2];
    const float* bq   = (const float*)d_in[3];
    const float* Wk   = (const float*)d_in[4];
    const float* bk   = (const float*)d_in[5];
    const float* Wv   = (const float*)d_in[6];
    const float* bv   = (const float*)d_in[7];
    const float* Wo   = (const float*)d_in[8];
    const float* bo   = (const float*)d_in[9];
    float* out = (float*)d_out;

    char* ws = (char*)d_ws;
    unsigned short* xb   = (unsigned short*)(ws);                   // 12582912
    unsigned short* wqkv = (unsigned short*)(ws + 12582912);        // 3538944
    unsigned short* wo   = (unsigned short*)(ws + 16121856);        // 1179648
    float*          biasq= (float*)(ws + 17301504);                 // 9216
    unsigned short* qb   = (unsigned short*)(ws + 17310720);        // 12582912
    unsigned short* kb   = (unsigned short*)(ws + 29893632);        // 12582912
    unsigned short* vtb  = (unsigned short*)(ws + 42476544);        // 12582912
    unsigned short* ctx  = (unsigned short*)(ws + 55059456);        // 12582912 -> ends 67642368

    pack_bf16<<<2048, 256, 0, stream>>>(x, xb, (MROWS * HDIM) / 4);
    pack_weights<<<2304, 256, 0, stream>>>(Wq, Wk, Wv, Wo, wqkv, wo);
    pack_bias<<<9, 256, 0, stream>>>(bq, bk, bv, biasq);

    gemm_bt<0><<<(MROWS / 128) * (NQKV / 128), 256, 0, stream>>>(
        xb, wqkv, biasq, qb, kb, vtb, nullptr, HDIM, NQKV / 128);

    attn_kernel<<<(SS / 64) * NH * BB, 256, 0, stream>>>(qb, kb, vtb, amask, ctx);

    gemm_bt<1><<<(MROWS / 128) * (HDIM / 128), 256, 0, stream>>>(
        ctx, wo, bo, nullptr, nullptr, nullptr, out, HDIM, HDIM / 128);
}

// Round 4
// 162.076 us; speedup vs baseline: 1.4017x; 1.1063x over previous
//
#include <hip/hip_runtime.h>
#include <hip/hip_bf16.h>

#define HDIM 768
#define NH 12
#define HD 64
#define BB 8
#define SS 1024
#define MROWS (BB*SS)      // 8192
#define NQKV (3*HDIM)      // 2304

typedef __attribute__((ext_vector_type(8))) short bf16x8;
typedef __attribute__((ext_vector_type(4))) float f32x4;

__device__ __forceinline__ unsigned short f2bf(float f) {
    unsigned int u = __float_as_uint(f);
    unsigned int r = (u + 0x7fffu + ((u >> 16) & 1u)) >> 16;   // RNE
    return (unsigned short)r;
}

__device__ __forceinline__ void gload_lds16(const void* gsrc, void* ldst) {
    __builtin_amdgcn_global_load_lds(
        (const __attribute__((address_space(1))) unsigned int*)gsrc,
        (__attribute__((address_space(3))) unsigned int*)ldst,
        16, 0, 0);
}

// ---------------- pack kernels ----------------
__global__ void pack_bf16(const float* __restrict__ src, unsigned short* __restrict__ dst, int n4) {
    int stride = gridDim.x * blockDim.x;
    for (int i = blockIdx.x * blockDim.x + threadIdx.x; i < n4; i += stride) {
        float4 v = reinterpret_cast<const float4*>(src)[i];
        union { unsigned short u[4]; unsigned long long q; } o;
        o.u[0] = f2bf(v.x); o.u[1] = f2bf(v.y); o.u[2] = f2bf(v.z); o.u[3] = f2bf(v.w);
        reinterpret_cast<unsigned long long*>(dst)[i] = o.q;
    }
}

// all 4 weight matrices in one launch: 4 segments x 576 blocks x 256 thr (147456 float4 each)
__global__ void pack_weights(const float* __restrict__ Wq, const float* __restrict__ Wk,
                             const float* __restrict__ Wv, const float* __restrict__ Wo,
                             unsigned short* __restrict__ wqkv, unsigned short* __restrict__ wo) {
    int seg = blockIdx.x / 576;
    int idx = (blockIdx.x % 576) * 256 + threadIdx.x;   // < 147456
    const float* src = (seg == 0) ? Wq : (seg == 1) ? Wk : (seg == 2) ? Wv : Wo;
    unsigned short* dst = (seg == 0) ? wqkv : (seg == 1) ? wqkv + HDIM * HDIM
                        : (seg == 2) ? wqkv + 2 * HDIM * HDIM : wo;
    float4 v = reinterpret_cast<const float4*>(src)[idx];
    union { unsigned short u[4]; unsigned long long q; } o;
    o.u[0] = f2bf(v.x); o.u[1] = f2bf(v.y); o.u[2] = f2bf(v.z); o.u[3] = f2bf(v.w);
    reinterpret_cast<unsigned long long*>(dst)[idx] = o.q;
}

__global__ void pack_bias(const float* __restrict__ bq, const float* __restrict__ bk,
                          const float* __restrict__ bv, float* __restrict__ dst) {
    int i = blockIdx.x * blockDim.x + threadIdx.x;
    if (i >= 3 * HDIM) return;
    float v = (i < HDIM) ? bq[i] : (i < 2 * HDIM) ? bk[i - HDIM] : bv[i - 2 * HDIM];
    dst[i] = v;
}

// ---------------- GEMM: C[m][n] = sum_k A[m][k] * Bw[n][k] + bias[n] ----------------
// 2-phase dbuf + T2 16B-granule XOR swizzle (granule ^= row&7) on both LDS tiles.
// Stage fetches pre-swizzled global granule (rule #21), reads XOR the same way.
// MODE 0: scatter to q [b][h][s][d], k [b][h][s][d], v^T [b][h][d][s] (bf16)
// MODE 1: fout[m*768 + n] = value (f32)
template<int MODE>
__global__ __launch_bounds__(256, 2)
void gemm_bt(const unsigned short* __restrict__ A,
             const unsigned short* __restrict__ Bw,
             const float* __restrict__ bias,
             unsigned short* __restrict__ qb,
             unsigned short* __restrict__ kb,
             unsigned short* __restrict__ vtb,
             float* __restrict__ fout,
             int K, int gridN)
{
    __shared__ unsigned short As[2][128 * 64];
    __shared__ unsigned short Bs[2][128 * 64];
    const int tid  = threadIdx.x;
    const int wave = tid >> 6;
    const int lane = tid & 63;

    // bijective XCD swizzle (nwg % 8 == 0), N-fastest within chunk
    const int nwg = gridDim.x;
    const int cpx = nwg >> 3;
    const int wg  = (blockIdx.x & 7) * cpx + (blockIdx.x >> 3);
    const int bm = (wg / gridN) * 128;
    const int bn = (wg % gridN) * 128;

    const int wm = (wave >> 1) * 64;
    const int wn = (wave & 1) * 64;
    const int lr  = lane & 15;
    const int hv  = lane >> 4;          // 0..3 (k-granule group)
    const int e3  = lr & 7;             // read-side row xor
    const int srow = lane >> 3;         // staging: row within 8-row group
    const int sg   = lane & 7;          // staging: LDS granule slot

    f32x4 zero4 = {0.f, 0.f, 0.f, 0.f};
    f32x4 acc[4][4];
#pragma unroll
    for (int i = 0; i < 4; i++)
#pragma unroll
        for (int j = 0; j < 4; j++) acc[i][j] = zero4;

    auto stage = [&](int buf, int k0) {
        const int gk = (sg ^ srow) * 8;     // pre-swizzled source granule (row&7 == srow)
#pragma unroll
        for (int jj = 0; jj < 4; ++jj) {
            int i = wave * 4 + jj;          // 0..15 row-groups of 8
            gload_lds16(A  + (size_t)(bm + i * 8 + srow) * K + k0 + gk, &As[buf][i * 8 * 64]);
            gload_lds16(Bw + (size_t)(bn + i * 8 + srow) * K + k0 + gk, &Bs[buf][i * 8 * 64]);
        }
    };

    stage(0, 0);
    __syncthreads();

    int buf = 0;
    for (int k0 = 0; k0 < K; k0 += 64) {
        if (k0 + 64 < K) stage(buf ^ 1, k0 + 64);

        bf16x8 af[4][2], bf[4][2];
#pragma unroll
        for (int mi = 0; mi < 4; mi++)
#pragma unroll
            for (int kk = 0; kk < 2; kk++)
                af[mi][kk] = *(const bf16x8*)
                    &As[buf][(wm + mi * 16 + lr) * 64 + ((kk * 4 + hv) ^ e3) * 8];
#pragma unroll
        for (int ni = 0; ni < 4; ni++)
#pragma unroll
            for (int kk = 0; kk < 2; kk++)
                bf[ni][kk] = *(const bf16x8*)
                    &Bs[buf][(wn + ni * 16 + lr) * 64 + ((kk * 4 + hv) ^ e3) * 8];

#pragma unroll
        for (int kk = 0; kk < 2; kk++)
#pragma unroll
            for (int mi = 0; mi < 4; mi++)
#pragma unroll
                for (int ni = 0; ni < 4; ni++)
                    acc[mi][ni] = __builtin_amdgcn_mfma_f32_16x16x32_bf16(
                        af[mi][kk], bf[ni][kk], acc[mi][ni], 0, 0, 0);

        __syncthreads();   // drains stage (vmcnt) + protects buffer being restaged next iter
        buf ^= 1;
    }

    const int rgrp = lane >> 4;   // 0..3
#pragma unroll
    for (int mi = 0; mi < 4; mi++)
#pragma unroll
        for (int ni = 0; ni < 4; ni++)
#pragma unroll
            for (int r = 0; r < 4; r++) {
                int m = bm + wm + mi * 16 + rgrp * 4 + r;
                int n = bn + wn + ni * 16 + lr;
                float v = acc[mi][ni][r] + bias[n];
                if (MODE == 0) {
                    int which = n / HDIM;
                    int nn = n - which * HDIM;
                    int h = nn >> 6, d = nn & 63;
                    int b = m >> 10, s = m & 1023;
                    unsigned short bvv = f2bf(v);
                    if (which == 0)      qb [(((size_t)(b * NH + h)) * SS + s) * HD + d] = bvv;
                    else if (which == 1) kb [(((size_t)(b * NH + h)) * SS + s) * HD + d] = bvv;
                    else                 vtb[(((size_t)(b * NH + h)) * HD + d) * SS + s] = bvv;
                } else {
                    fout[(size_t)m * HDIM + n] = v;
                }
            }
}

// ---------------- flash attention (swapped-QK^T, swizzled LDS, double-buffered) ----------------
// grid: 1536 blocks (flattened b,h,qt with XCD swizzle), block 256 (4 waves x 16 q-rows)
__global__ __launch_bounds__(256)
void attn_kernel(const unsigned short* __restrict__ qb,
                 const unsigned short* __restrict__ kb,
                 const unsigned short* __restrict__ vtb,
                 const int* __restrict__ mask,
                 unsigned short* __restrict__ ctx)
{
    __shared__ unsigned short Ks[2][64][64];   // [buf][token][d]
    __shared__ unsigned short Vs[2][64][64];   // [buf][d][token]
    __shared__ unsigned short Ps[4][16][64];   // per-wave P [q][token], 8B-chunk swizzle

    const int tid  = threadIdx.x;
    const int wave = tid >> 6;
    const int lane = tid & 63;
    // XCD swizzle: each XCD gets one full batch (12 heads x 16 q-tiles -> K/V fits 4MB L2)
    const int wg = (blockIdx.x & 7) * 192 + (blockIdx.x >> 3);
    const int qt = wg & 15;
    const int h  = (wg >> 4) % NH;
    const int b  = wg / 192;
    const int bh = b * NH + h;
    const int q0 = qt * 64 + wave * 16;
    const int lr  = lane & 15;
    const int hi  = lane >> 4;          // 0..3
    const int e3  = lr & 7;             // read-side row xor
    const int srow = lane >> 3;         // staging: row within 8-row group
    const int sg   = lane & 7;          // staging: LDS granule index

    const unsigned short* Qp = qb  + (size_t)bh * SS * HD;
    const unsigned short* Kp = kb  + (size_t)bh * SS * HD;
    const unsigned short* Vp = vtb + (size_t)bh * HD * SS;

    bf16x8 aq[2];
#pragma unroll
    for (int kk = 0; kk < 2; kk++)
        aq[kk] = *(const bf16x8*)&Qp[(size_t)(q0 + lr) * HD + kk * 32 + hi * 8];

    f32x4 zero4 = {0.f, 0.f, 0.f, 0.f};
    f32x4 o[4];
#pragma unroll
    for (int i = 0; i < 4; i++) o[i] = zero4;
    float mrun = -__builtin_inff();
    float lrun = 0.f;

    auto stage = [&](int buf, int t0) {
#pragma unroll
        for (int jj = 0; jj < 2; ++jj) {
            int i = wave * 2 + jj;               // 0..7
            int rr = i * 8 + srow;               // row 0..63
            int gk = sg ^ (rr & 7);              // pre-swizzled source granule
            gload_lds16(Kp + (size_t)(t0 + rr) * HD + gk * 8, &Ks[buf][i * 8][0]);
            gload_lds16(Vp + (size_t)rr * SS + t0 + gk * 8,   &Vs[buf][i * 8][0]);
        }
    };

    stage(0, 0);
    __syncthreads();

    int buf = 0;
    for (int t0 = 0; t0 < SS; t0 += 64) {
        if (t0 + 64 < SS) stage(buf ^ 1, t0 + 64);

        // QK^T swapped: row = token(ni*16+4hi+r), col = q(lr)
        f32x4 sacc[4];
#pragma unroll
        for (int ni = 0; ni < 4; ni++) sacc[ni] = zero4;
#pragma unroll
        for (int kk = 0; kk < 2; kk++)
#pragma unroll
            for (int ni = 0; ni < 4; ni++) {
                bf16x8 kf = *(const bf16x8*)&Ks[buf][ni * 16 + lr][((kk * 4 + hi) ^ e3) * 8];
                sacc[ni] = __builtin_amdgcn_mfma_f32_16x16x32_bf16(kf, aq[kk], sacc[ni], 0, 0, 0);
            }

        int4 mv[4];
#pragma unroll
        for (int ni = 0; ni < 4; ni++)
            mv[ni] = *(const int4*)&mask[b * SS + t0 + ni * 16 + hi * 4];

        float sc[4][4];
        float vmax = -__builtin_inff();
#pragma unroll
        for (int ni = 0; ni < 4; ni++) {
            sc[ni][0] = (mv[ni].x == 0) ? -10000.0f : sacc[ni][0] * 0.125f;
            sc[ni][1] = (mv[ni].y == 0) ? -10000.0f : sacc[ni][1] * 0.125f;
            sc[ni][2] = (mv[ni].z == 0) ? -10000.0f : sacc[ni][2] * 0.125f;
            sc[ni][3] = (mv[ni].w == 0) ? -10000.0f : sacc[ni][3] * 0.125f;
#pragma unroll
            for (int r = 0; r < 4; r++) vmax = fmaxf(vmax, sc[ni][r]);
        }
        vmax = fmaxf(vmax, __shfl_xor(vmax, 16));
        vmax = fmaxf(vmax, __shfl_xor(vmax, 32));

        float mnew  = fmaxf(mrun, vmax);
        float alpha = __expf(mrun - mnew);
        float psum = 0.f;
#pragma unroll
        for (int ni = 0; ni < 4; ni++)
#pragma unroll
            for (int r = 0; r < 4; r++) {
                float e = __expf(sc[ni][r] - mnew);
                sc[ni][r] = e;
                psum += e;
            }
        psum += __shfl_xor(psum, 16);
        psum += __shfl_xor(psum, 32);
        lrun = lrun * alpha + psum;
        mrun = mnew;

#pragma unroll
        for (int ni = 0; ni < 4; ni++) {
            unsigned long long w =
                (unsigned long long)f2bf(sc[ni][0])
              | ((unsigned long long)f2bf(sc[ni][1]) << 16)
              | ((unsigned long long)f2bf(sc[ni][2]) << 32)
              | ((unsigned long long)f2bf(sc[ni][3]) << 48);
            *(unsigned long long*)&Ps[wave][lr][((4 * ni + hi) ^ (e3 << 1)) * 4] = w;
        }

        float aR[4];
#pragma unroll
        for (int r = 0; r < 4; r++) aR[r] = __shfl(alpha, hi * 4 + r, 16);
#pragma unroll
        for (int nd = 0; nd < 4; nd++)
#pragma unroll
            for (int r = 0; r < 4; r++) o[nd][r] *= aR[r];

#pragma unroll
        for (int ks = 0; ks < 2; ks++) {
            bf16x8 pa = *(const bf16x8*)&Ps[wave][lr][((8 * ks + 2 * hi) ^ (e3 << 1)) * 4];
#pragma unroll
            for (int nd = 0; nd < 4; nd++) {
                bf16x8 vb = *(const bf16x8*)&Vs[buf][nd * 16 + lr][((4 * ks + hi) ^ e3) * 8];
                o[nd] = __builtin_amdgcn_mfma_f32_16x16x32_bf16(pa, vb, o[nd], 0, 0, 0);
            }
        }

        __syncthreads();
        buf ^= 1;
    }

    float iv[4];
#pragma unroll
    for (int r = 0; r < 4; r++) iv[r] = 1.0f / __shfl(lrun, hi * 4 + r, 16);
#pragma unroll
    for (int r = 0; r < 4; r++) {
        int grow = b * SS + qt * 64 + wave * 16 + hi * 4 + r;
#pragma unroll
        for (int nd = 0; nd < 4; nd++)
            ctx[(size_t)grow * HDIM + h * HD + nd * 16 + lr] = f2bf(o[nd][r] * iv[r]);
    }
}

// ---------------- launch ----------------
extern "C" void kernel_launch(void* const* d_in, const int* in_sizes, int n_in,
                              void* d_out, int out_size, void* d_ws, size_t ws_size,
                              hipStream_t stream)
{
    const float* x    = (const float*)d_in[0];
    const int*   amask= (const int*)d_in[1];
    const float* Wq   = (const float*)d_in[2];
    const float* bq   = (const float*)d_in[3];
    const float* Wk   = (const float*)d_in[4];
    const float* bk   = (const float*)d_in[5];
    const float* Wv   = (const float*)d_in[6];
    const float* bv   = (const float*)d_in[7];
    const float* Wo   = (const float*)d_in[8];
    const float* bo   = (const float*)d_in[9];
    float* out = (float*)d_out;

    char* ws = (char*)d_ws;
    unsigned short* xb   = (unsigned short*)(ws);                   // 12582912
    unsigned short* wqkv = (unsigned short*)(ws + 12582912);        // 3538944
    unsigned short* wo   = (unsigned short*)(ws + 16121856);        // 1179648
    float*          biasq= (float*)(ws + 17301504);                 // 9216
    unsigned short* qb   = (unsigned short*)(ws + 17310720);        // 12582912
    unsigned short* kb   = (unsigned short*)(ws + 29893632);        // 12582912
    unsigned short* vtb  = (unsigned short*)(ws + 42476544);        // 12582912
    unsigned short* ctx  = (unsigned short*)(ws + 55059456);        // 12582912 -> ends 67642368

    pack_bf16<<<2048, 256, 0, stream>>>(x, xb, (MROWS * HDIM) / 4);
    pack_weights<<<2304, 256, 0, stream>>>(Wq, Wk, Wv, Wo, wqkv, wo);
    pack_bias<<<9, 256, 0, stream>>>(bq, bk, bv, biasq);

    gemm_bt<0><<<(MROWS / 128) * (NQKV / 128), 256, 0, stream>>>(
        xb, wqkv, biasq, qb, kb, vtb, nullptr, HDIM, NQKV / 128);

    attn_kernel<<<(SS / 64) * NH * BB, 256, 0, stream>>>(qb, kb, vtb, amask, ctx);

    gemm_bt<1><<<(MROWS / 128) * (HDIM / 128), 256, 0, stream>>>(
        ctx, wo, bo, nullptr, nullptr, nullptr, out, HDIM, HDIM / 128);
}